// Round 12
// baseline (109.981 us; speedup 1.0000x reference)
//
#include <hip/hip_runtime.h>

// Output layout (floats): [0]=loss, [1..8388608]=quantized BCHW,
// [8388609]=perplexity, [8388610..]=encodings (N x K)
#define QUANT_OFF 1
#define PERP_OFF 8388609
#define ENC_OFF  8388610

// ws: [0,2048)     counts u32[512]
//     [2048,4096)  sw2 f32[512]
//     [4096,12288) lpart f32[2048]  (one per wave)
//     [12288,77824) w2 bf16[512*64] (-2W)

typedef __attribute__((ext_vector_type(8))) short bf16x8;
typedef __attribute__((ext_vector_type(2))) float f32x2;
typedef __attribute__((ext_vector_type(4))) float f32x4;

__device__ __forceinline__ unsigned short f2bf(float f) {
  unsigned int u = __float_as_uint(f);
  u += 0x7fffu + ((u >> 16) & 1u);
  return (unsigned short)(u >> 16);
}

// 512 blocks x 64 thr: sw2, bf16(-2W) pack, counts zeroing
__global__ void vq_prep(const float* __restrict__ W, float* __restrict__ sw2,
                        unsigned short* __restrict__ w2,
                        unsigned int* __restrict__ counts) {
  int k = blockIdx.x;
  int d = threadIdx.x;
  float wd = W[k * 64 + d];
  w2[k * 64 + d] = f2bf(-2.0f * wd);
  float s = wd * wd;
  #pragma unroll
  for (int off = 32; off; off >>= 1) s += __shfl_down(s, off, 64);
  if (d == 0) { sw2[k] = s; counts[k] = 0u; }
}

// NO LDS, NO BARRIERS. 256 thr = 4 independent waves; wave owns 64 points
// (4 column-sets sharing every A-frag load). A-frags stream from L1/L2
// (w2 = 64KB bf16). Each wave: argmin -> enc rows (128KB contiguous) ->
// quant (coalesced) -> bookkeeping. Waves drift; stores overlap compute.
__global__ __launch_bounds__(256) void vq_fused(
    const float* __restrict__ x, const unsigned short* __restrict__ w2,
    const float* __restrict__ sw2g, const float* __restrict__ W,
    unsigned int* __restrict__ counts, float* __restrict__ lpart,
    float* __restrict__ out) {
  int tid  = threadIdx.x;
  int lane = tid & 63;
  int wid  = blockIdx.x * 4 + (tid >> 6);   // global wave id, 2048 waves
  int rl   = lane & 15;        // column within set / code-row-in-tile
  int g    = lane >> 4;        // k-group (8 dims) / acc row-group
  int n0   = wid << 6;         // wave's 64 points (never cross a batch)
  int b    = n0 >> 12;
  int hw0  = n0 & 4095;
  const float* xb = x + b * 262144 + hw0;   // channel stride 4096

  // ---- x frags: 4 sets x 16 dims per lane, bf16 + ||x||^2 partials
  bf16x8 xa0, xa1, xb0, xb1, xc0, xc1, xd0, xd1;
  float cnA = 0.f, cnB = 0.f, cnC = 0.f, cnD = 0.f;
  #pragma unroll
  for (int e = 0; e < 8; ++e) {
    int d0 = (g * 8 + e) * 4096, d1 = (32 + g * 8 + e) * 4096;
    float a0 = xb[d0 + rl],      a1 = xb[d1 + rl];
    float b0 = xb[d0 + 16 + rl], b1 = xb[d1 + 16 + rl];
    float c0 = xb[d0 + 32 + rl], c1 = xb[d1 + 32 + rl];
    float e0 = xb[d0 + 48 + rl], e1 = xb[d1 + 48 + rl];
    cnA = fmaf(a0, a0, fmaf(a1, a1, cnA));
    cnB = fmaf(b0, b0, fmaf(b1, b1, cnB));
    cnC = fmaf(c0, c0, fmaf(c1, c1, cnC));
    cnD = fmaf(e0, e0, fmaf(e1, e1, cnD));
    xa0[e] = f2bf(a0); xa1[e] = f2bf(a1);
    xb0[e] = f2bf(b0); xb1[e] = f2bf(b1);
    xc0[e] = f2bf(c0); xc1[e] = f2bf(c1);
    xd0[e] = f2bf(e0); xd1[e] = f2bf(e1);
  }
  cnA += __shfl_xor(cnA, 16); cnA += __shfl_xor(cnA, 32);
  cnB += __shfl_xor(cnB, 16); cnB += __shfl_xor(cnB, 32);
  cnC += __shfl_xor(cnC, 16); cnC += __shfl_xor(cnC, 32);
  cnD += __shfl_xor(cnD, 16); cnD += __shfl_xor(cnD, 32);

  // ---- 32 code-tiles from L1/L2; shared A-frags feed 4 sets (8 MFMA/tile)
  float bA = __uint_as_float(0x7f7fffffu), bB = bA, bC = bA, bD = bA;
  int abase = rl * 64 + g * 8;    // ushort offset within a tile's 16 rows
  #pragma unroll 4
  for (int t = 0; t < 32; ++t) {
    f32x4 sv = *(const f32x4*)&sw2g[t * 16 + g * 4];
    const unsigned short* wt = w2 + (t << 10) + abase;
    bf16x8 a0 = *(const bf16x8*)wt;          // dims [g*8, g*8+8)
    bf16x8 a1 = *(const bf16x8*)(wt + 32);   // dims [32+g*8, ...)
    f32x4 pA = sv, pB = sv, pC = sv, pD = sv;
    pA = __builtin_amdgcn_mfma_f32_16x16x32_bf16(a0, xa0, pA, 0, 0, 0);
    pA = __builtin_amdgcn_mfma_f32_16x16x32_bf16(a1, xa1, pA, 0, 0, 0);
    pB = __builtin_amdgcn_mfma_f32_16x16x32_bf16(a0, xb0, pB, 0, 0, 0);
    pB = __builtin_amdgcn_mfma_f32_16x16x32_bf16(a1, xb1, pB, 0, 0, 0);
    pC = __builtin_amdgcn_mfma_f32_16x16x32_bf16(a0, xc0, pC, 0, 0, 0);
    pC = __builtin_amdgcn_mfma_f32_16x16x32_bf16(a1, xc1, pC, 0, 0, 0);
    pD = __builtin_amdgcn_mfma_f32_16x16x32_bf16(a0, xd0, pD, 0, 0, 0);
    pD = __builtin_amdgcn_mfma_f32_16x16x32_bf16(a1, xd1, pD, 0, 0, 0);
    #pragma unroll
    for (int j = 0; j < 4; ++j) {
      unsigned int ki = (unsigned int)(t * 16 + g * 4 + j);
      bA = fminf(bA, __uint_as_float((__float_as_uint(pA[j]) & ~511u) | ki));
      bB = fminf(bB, __uint_as_float((__float_as_uint(pB[j]) & ~511u) | ki));
      bC = fminf(bC, __uint_as_float((__float_as_uint(pC[j]) & ~511u) | ki));
      bD = fminf(bD, __uint_as_float((__float_as_uint(pD[j]) & ~511u) | ki));
    }
  }
  bA = fminf(bA, __shfl_xor(bA, 16)); bA = fminf(bA, __shfl_xor(bA, 32));
  bB = fminf(bB, __shfl_xor(bB, 16)); bB = fminf(bB, __shfl_xor(bB, 32));
  bC = fminf(bC, __shfl_xor(bC, 16)); bC = fminf(bC, __shfl_xor(bC, 32));
  bD = fminf(bD, __shfl_xor(bD, 16)); bD = fminf(bD, __shfl_xor(bD, 32));

  // lane's own point = lane (= g*16 + rl): select its set's result
  float bsel = (g == 0) ? bA : (g == 1) ? bB : (g == 2) ? bC : bD;
  float cnsel = (g == 0) ? cnA : (g == 1) ? cnB : (g == 2) ? cnC : cnD;
  int   bisel = __float_as_uint(bsel) & 511;
  float scsel = __uint_as_float(__float_as_uint(bsel) & ~511u);

  // histogram: one integer atomic per point (deterministic)
  atomicAdd(&counts[bisel], 1u);

  // loss: per-wave slot, no float atomics
  float dl = cnsel + scsel;
  #pragma unroll
  for (int off = 1; off < 64; off <<= 1) dl += __shfl_xor(dl, off);
  if (lane == 0) lpart[wid] = dl;

  // ---- enc one-hot: 64 rows = 128KB contiguous, fire-and-forget
  {
    f32x2* encw = (f32x2*)(out + ENC_OFF) + ((long long)n0 << 8);
    #pragma unroll 4
    for (int r = 0; r < 64; ++r) {
      int rb = __shfl(bisel, r);
      f32x2* rowp = encw + (r << 8);
      #pragma unroll
      for (int q = 0; q < 4; ++q) {
        int ci = ((q << 6) + lane) << 1;
        f32x2 v;
        v.x = (rb == ci)     ? 1.0f : 0.0f;
        v.y = (rb == ci + 1) ? 1.0f : 0.0f;
        rowp[(q << 6) + lane] = v;
      }
    }
  }

  // ---- quant: lane owns point `lane`; W-row float4 gather (L2-hot),
  // stores 256B-coalesced across lanes per channel
  {
    float* qp = out + QUANT_OFF + b * 262144 + hw0 + lane;
    const float4* wr4 = (const float4*)W + (bisel << 4);
    #pragma unroll 4
    for (int cq = 0; cq < 16; ++cq) {
      float4 wv = wr4[cq];
      qp[(cq * 4 + 0) * 4096] = wv.x;
      qp[(cq * 4 + 1) * 4096] = wv.y;
      qp[(cq * 4 + 2) * 4096] = wv.z;
      qp[(cq * 4 + 3) * 4096] = wv.w;
    }
  }
}

// Tiny finalizer: perplexity from counts, loss from 2048 wave partials.
__global__ void vq_final(const unsigned int* __restrict__ counts,
                         const float* __restrict__ lpart,
                         float* __restrict__ out) {
  __shared__ float red[8], red2[8];
  int k = threadIdx.x;  // 512 threads
  float pr = (float)counts[k] * (1.0f / 131072.0f);
  float s = pr * logf(pr + 1e-10f);
  float l = lpart[k] + lpart[k + 512] + lpart[k + 1024] + lpart[k + 1536];
  #pragma unroll
  for (int off = 32; off; off >>= 1) {
    s += __shfl_down(s, off, 64);
    l += __shfl_down(l, off, 64);
  }
  if ((k & 63) == 0) { red[k >> 6] = s; red2[k >> 6] = l; }
  __syncthreads();
  if (k == 0) {
    float H = 0.0f, L = 0.0f;
    #pragma unroll
    for (int i = 0; i < 8; ++i) { H += red[i]; L += red2[i]; }
    out[PERP_OFF] = expf(-H);
    out[0] = 1.25f * L * (1.0f / 8388608.0f);
  }
}

extern "C" void kernel_launch(void* const* d_in, const int* in_sizes, int n_in,
                              void* d_out, int out_size, void* d_ws, size_t ws_size,
                              hipStream_t stream) {
  (void)in_sizes; (void)n_in; (void)out_size; (void)ws_size;
  const float* x = (const float*)d_in[0];
  const float* W = (const float*)d_in[1];
  float* out = (float*)d_out;

  char* ws = (char*)d_ws;
  unsigned int* counts = (unsigned int*)ws;
  float* sw2           = (float*)(ws + 2048);
  float* lpart         = (float*)(ws + 4096);
  unsigned short* w2   = (unsigned short*)(ws + 12288);

  vq_prep<<<512, 64, 0, stream>>>(W, sw2, w2, counts);
  vq_fused<<<512, 256, 0, stream>>>(x, w2, sw2, W, counts, lpart, out);
  vq_final<<<1, 512, 0, stream>>>(counts, lpart, out);
}

// Round 13
// 98.942 us; speedup vs baseline: 1.1116x; 1.1116x over previous
//
#include <hip/hip_runtime.h>

// Output layout (floats): [0]=loss, [1..8388608]=quantized BCHW,
// [8388609]=perplexity, [8388610..]=encodings (N x K)
#define QUANT_OFF 1
#define PERP_OFF 8388609
#define ENC_OFF  8388610

// ws: [0,2048)    counts u32[512]
//     [2048,4096) sw2 f32[512]
//     [4096,6144) lpart f32[512]
//     [8192,73728) w2 bf16[512*64]  (-2W)

typedef __attribute__((ext_vector_type(8))) short bf16x8;
typedef __attribute__((ext_vector_type(4))) float f32x4;

__device__ __forceinline__ unsigned short f2bf(float f) {
  unsigned int u = __float_as_uint(f);
  u += 0x7fffu + ((u >> 16) & 1u);
  return (unsigned short)(u >> 16);
}

// 512 blocks x 64 thr: sw2, bf16(-2W) pack, counts zeroing
__global__ void vq_prep(const float* __restrict__ W, float* __restrict__ sw2,
                        unsigned short* __restrict__ w2,
                        unsigned int* __restrict__ counts) {
  int k = blockIdx.x;
  int d = threadIdx.x;
  float wd = W[k * 64 + d];
  w2[k * 64 + d] = f2bf(-2.0f * wd);
  float s = wd * wd;
  #pragma unroll
  for (int off = 32; off; off >>= 1) s += __shfl_down(s, off, 64);
  if (d == 0) { sw2[k] = s; counts[k] = 0u; }
}

// 512 thr = 8 waves; wave owns 32 points; grid = 512 (2 blocks/CU).
// KEY: the wave's 64KB of enc ZEROS (dependency-free) stream out DURING
// the MFMA loop; after argmin only 1 dword/point (the 1.0) remains.
// Compute loop has NO VMEM loads (sw2 in LDS) so the in-flight zero
// stores never gate compute via the FIFO vmcnt. Quant fused in tail.
__global__ __launch_bounds__(512, 4) void vq_main(
    const float* __restrict__ x, const unsigned short* __restrict__ w2,
    const float* __restrict__ sw2g, const float* __restrict__ W,
    unsigned int* __restrict__ counts, float* __restrict__ lpart,
    float* __restrict__ out) {
  __shared__ unsigned short wlds[512 * 72];  // 73728 B, padded rows
  __shared__ float sw2s[512];
  __shared__ float lred[8];

  int tid  = threadIdx.x;
  int lane = tid & 63;
  int wv   = tid >> 6;
  int rl   = lane & 15;        // column (point-in-set) / code-row-in-tile
  int g    = lane >> 4;        // k-group (8 dims) / acc row-group
  int n0   = (blockIdx.x << 8) + (wv << 5);   // wave's 32 points
  int b    = n0 >> 12;         // 256-pt blocks never cross a batch
  int hw0  = n0 & 4095;
  const float* xb = x + b * 262144 + hw0;     // channel stride 4096

  // ---- issue staging loads first (regs), then x loads (all before stores)
  bf16x8 st[8];
  #pragma unroll
  for (int i = 0; i < 8; ++i) st[i] = *(const bf16x8*)&w2[(((i << 9) + tid)) * 8];

  bf16x8 xfA0, xfA1, xfB0, xfB1;
  float cnA = 0.0f, cnB = 0.0f;
  #pragma unroll
  for (int e = 0; e < 8; ++e) {
    int d0 = (g * 8 + e) * 4096, d1 = (32 + g * 8 + e) * 4096;
    float a0 = xb[d0 + rl],      a1 = xb[d1 + rl];
    float b0 = xb[d0 + 16 + rl], b1 = xb[d1 + 16 + rl];
    cnA = fmaf(a0, a0, fmaf(a1, a1, cnA));
    cnB = fmaf(b0, b0, fmaf(b1, b1, cnB));
    xfA0[e] = f2bf(a0); xfA1[e] = f2bf(a1);
    xfB0[e] = f2bf(b0); xfB1[e] = f2bf(b1);
  }
  cnA += __shfl_xor(cnA, 16); cnA += __shfl_xor(cnA, 32);
  cnB += __shfl_xor(cnB, 16); cnB += __shfl_xor(cnB, 32);

  // ---- LDS writes (padded rows: stride 72 ushorts)
  #pragma unroll
  for (int i = 0; i < 8; ++i) {
    int u = (i << 9) + tid;
    int r = u >> 3, c = u & 7;
    *(bf16x8*)&wlds[r * 72 + c * 8] = st[i];
  }
  sw2s[tid] = sw2g[tid];
  __syncthreads();

  // ---- main loop: 4 groups x (16 enc-zero stores + 8 tiles)
  float4* encq = (float4*)(out + ENC_OFF) + ((long long)n0 << 7);
  float4 z4 = make_float4(0.f, 0.f, 0.f, 0.f);
  float bestA = __uint_as_float(0x7f7fffffu);
  float bestB = __uint_as_float(0x7f7fffffu);
  int rowoff = rl * 72 + g * 8;

  for (int grp = 0; grp < 4; ++grp) {
    #pragma unroll
    for (int i = 0; i < 16; ++i)
      encq[((grp << 4) + i) * 64 + lane] = z4;   // fire-and-forget zeros

    #pragma unroll
    for (int tt = 0; tt < 8; ++tt) {
      int t = (grp << 3) + tt;
      f32x4 sv = *(const f32x4*)&sw2s[t * 16 + g * 4];
      int tb = t * 1152 + rowoff;
      bf16x8 a0 = *(const bf16x8*)&wlds[tb];
      bf16x8 a1 = *(const bf16x8*)&wlds[tb + 32];
      f32x4 accA = sv, accB = sv;
      accA = __builtin_amdgcn_mfma_f32_16x16x32_bf16(a0, xfA0, accA, 0, 0, 0);
      accA = __builtin_amdgcn_mfma_f32_16x16x32_bf16(a1, xfA1, accA, 0, 0, 0);
      accB = __builtin_amdgcn_mfma_f32_16x16x32_bf16(a0, xfB0, accB, 0, 0, 0);
      accB = __builtin_amdgcn_mfma_f32_16x16x32_bf16(a1, xfB1, accB, 0, 0, 0);
      #pragma unroll
      for (int j = 0; j < 4; ++j) {
        unsigned int ki = (unsigned int)(t * 16 + g * 4 + j);
        bestA = fminf(bestA, __uint_as_float((__float_as_uint(accA[j]) & ~511u) | ki));
        bestB = fminf(bestB, __uint_as_float((__float_as_uint(accB[j]) & ~511u) | ki));
      }
    }
  }
  bestA = fminf(bestA, __shfl_xor(bestA, 16));
  bestA = fminf(bestA, __shfl_xor(bestA, 32));
  bestB = fminf(bestB, __shfl_xor(bestB, 16));
  bestB = fminf(bestB, __shfl_xor(bestB, 32));
  int biA = __float_as_uint(bestA) & 511;   // result for point n0+rl
  int biB = __float_as_uint(bestB) & 511;   // result for point n0+16+rl
  float scoreA = __uint_as_float(__float_as_uint(bestA) & ~511u);
  float scoreB = __uint_as_float(__float_as_uint(bestB) & ~511u);

  // ---- all this wave's zero stores retired -> safe to drop the 1.0s
  asm volatile("s_waitcnt vmcnt(0)" ::: "memory");
  if (lane < 32) {
    int p  = lane & 15;
    int bi = (lane < 16) ? biA : biB;
    int n  = n0 + ((lane < 16) ? p : 16 + p);
    out[ENC_OFF + ((long long)n << 9) + bi] = 1.0f;
  }

  // ---- quant: 2 lanes/point, 32 channels each; W rows L1/L2-hot
  {
    int p = lane & 31, half = lane >> 5;
    int bip = (p < 16) ? __shfl(biA, p) : __shfl(biB, p - 16);
    const float4* wr4 = (const float4*)W + (bip << 4) + (half << 3);
    float* qp = out + QUANT_OFF + b * 262144 + (half << 5) * 4096 + hw0 + p;
    #pragma unroll
    for (int cq = 0; cq < 8; ++cq) {
      float4 wv4 = wr4[cq];
      qp[(cq * 4 + 0) * 4096] = wv4.x;
      qp[(cq * 4 + 1) * 4096] = wv4.y;
      qp[(cq * 4 + 2) * 4096] = wv4.z;
      qp[(cq * 4 + 3) * 4096] = wv4.w;
    }
  }

  // ---- bookkeeping
  if (lane < 16)      atomicAdd(&counts[biA], 1u);
  else if (lane < 32) atomicAdd(&counts[biB], 1u);

  float dl = (cnA + scoreA) + (cnB + scoreB);   // 4 copies/point in wave
  #pragma unroll
  for (int off = 1; off < 64; off <<= 1) dl += __shfl_xor(dl, off);
  if (lane == 0) lred[wv] = dl * 0.25f;
  __syncthreads();
  if (tid == 0) {
    float s = 0.0f;
    #pragma unroll
    for (int i = 0; i < 8; ++i) s += lred[i];
    lpart[blockIdx.x] = s;
  }
}

// Tiny finalizer: perplexity from counts, loss from 512 block partials.
__global__ void vq_final(const unsigned int* __restrict__ counts,
                         const float* __restrict__ lpart,
                         float* __restrict__ out) {
  __shared__ float red[8], red2[8];
  int k = threadIdx.x;  // 512 threads
  float pr = (float)counts[k] * (1.0f / 131072.0f);
  float s = pr * logf(pr + 1e-10f);
  float l = lpart[k];
  #pragma unroll
  for (int off = 32; off; off >>= 1) {
    s += __shfl_down(s, off, 64);
    l += __shfl_down(l, off, 64);
  }
  if ((k & 63) == 0) { red[k >> 6] = s; red2[k >> 6] = l; }
  __syncthreads();
  if (k == 0) {
    float H = 0.0f, L = 0.0f;
    #pragma unroll
    for (int i = 0; i < 8; ++i) { H += red[i]; L += red2[i]; }
    out[PERP_OFF] = expf(-H);
    out[0] = 1.25f * L * (1.0f / 8388608.0f);
  }
}

extern "C" void kernel_launch(void* const* d_in, const int* in_sizes, int n_in,
                              void* d_out, int out_size, void* d_ws, size_t ws_size,
                              hipStream_t stream) {
  (void)in_sizes; (void)n_in; (void)out_size; (void)ws_size;
  const float* x = (const float*)d_in[0];
  const float* W = (const float*)d_in[1];
  float* out = (float*)d_out;

  char* ws = (char*)d_ws;
  unsigned int* counts = (unsigned int*)ws;
  float* sw2           = (float*)(ws + 2048);
  float* lpart         = (float*)(ws + 4096);
  unsigned short* w2   = (unsigned short*)(ws + 8192);

  vq_prep<<<512, 64, 0, stream>>>(W, sw2, w2, counts);
  vq_main<<<512, 512, 0, stream>>>(x, w2, sw2, W, counts, lpart, out);
  vq_final<<<1, 512, 0, stream>>>(counts, lpart, out);
}

// Round 14
// 81.387 us; speedup vs baseline: 1.3513x; 1.2157x over previous
//
#include <hip/hip_runtime.h>

// Output layout (floats): [0]=loss, [1..8388608]=quantized BCHW,
// [8388609]=perplexity, [8388610..]=encodings (N x K)
#define QUANT_OFF 1
#define PERP_OFF 8388609
#define ENC_OFF  8388610

// ws: [0,2048)    counts u32[512]
//     [2048,4096) sw2 f32[512]
//     [4096,6144) lpart f32[512]
//     [8192,73728) w2 bf16[512*64]  (-2W)

typedef __attribute__((ext_vector_type(8))) short bf16x8;
typedef __attribute__((ext_vector_type(4))) float f32x4;

__device__ __forceinline__ unsigned short f2bf(float f) {
  unsigned int u = __float_as_uint(f);
  u += 0x7fffu + ((u >> 16) & 1u);
  return (unsigned short)(u >> 16);
}

// 512 blocks x 64 thr: sw2, bf16(-2W) pack, counts zeroing
__global__ void vq_prep(const float* __restrict__ W, float* __restrict__ sw2,
                        unsigned short* __restrict__ w2,
                        unsigned int* __restrict__ counts) {
  int k = blockIdx.x;
  int d = threadIdx.x;
  float wd = W[k * 64 + d];
  w2[k * 64 + d] = f2bf(-2.0f * wd);
  float s = wd * wd;
  #pragma unroll
  for (int off = 32; off; off >>= 1) s += __shfl_down(s, off, 64);
  if (d == 0) { sw2[k] = s; counts[k] = 0u; }
}

// 1024 thr = 16 waves, 2 blocks/CU, grid 512 (single round).
// WAVE SPECIALIZATION: waves 0-7 = compute (R10 argmin core, 256 points),
// waves 8-15 = fillers streaming the block's 512KB of enc zeros DURING the
// MFMA loop. Store-issue stalls park only filler waves; compute waves have
// no big stores -> true overlap. barrier2 drains fillers (zeros visible),
// then all 16 waves write the 1.0s + quantized + flush bookkeeping.
__global__ __launch_bounds__(1024, 8) void vq_mega(
    const float* __restrict__ x, const unsigned short* __restrict__ w2,
    const float* __restrict__ sw2g, const float* __restrict__ W,
    unsigned int* __restrict__ counts, float* __restrict__ lpart,
    float* __restrict__ out) {
  __shared__ unsigned short wlds[512 * 72];  // 73728 B, padded rows
  __shared__ float sw2s[512];
  __shared__ unsigned int hcnt[512];
  __shared__ int   sbi[256];
  __shared__ float lred[8];

  int tid  = threadIdx.x;
  int lane = tid & 63;
  int wv   = tid >> 6;          // 0..15
  int nb0  = blockIdx.x << 8;   // block's first point (256/block)
  int b    = nb0 >> 12;         // never crosses a batch
  int hw0b = nb0 & 4095;

  if (tid < 512) hcnt[tid] = 0u;

  bf16x8 xfA0, xfA1, xfB0, xfB1;
  float cnA = 0.0f, cnB = 0.0f;
  int rl = lane & 15, g = lane >> 4;

  if (wv < 8) {
    // ---- compute waves: x frags + W staging ----
    int n0  = nb0 + (wv << 5);          // wave's 32 points
    int hw0 = n0 & 4095;
    const float* xb = x + b * 262144 + hw0;
    #pragma unroll
    for (int e = 0; e < 8; ++e) {
      int d0 = (g * 8 + e) * 4096, d1 = (32 + g * 8 + e) * 4096;
      float a0 = xb[d0 + rl],      a1 = xb[d1 + rl];
      float b0 = xb[d0 + 16 + rl], b1 = xb[d1 + 16 + rl];
      cnA = fmaf(a0, a0, fmaf(a1, a1, cnA));
      cnB = fmaf(b0, b0, fmaf(b1, b1, cnB));
      xfA0[e] = f2bf(a0); xfA1[e] = f2bf(a1);
      xfB0[e] = f2bf(b0); xfB1[e] = f2bf(b1);
    }
    cnA += __shfl_xor(cnA, 16); cnA += __shfl_xor(cnA, 32);
    cnB += __shfl_xor(cnB, 16); cnB += __shfl_xor(cnB, 32);

    // stage bf16 (-2W) into padded LDS: 8 units per thread over 512 threads
    int ct = (wv << 6) + lane;          // 0..511
    #pragma unroll
    for (int i = 0; i < 8; ++i) {
      int u = (i << 9) + ct;            // 4096 units of 8 bf16
      int r = u >> 3, c = u & 7;
      *(bf16x8*)&wlds[r * 72 + c * 8] = *(const bf16x8*)&w2[u * 8];
    }
    sw2s[ct] = sw2g[ct];
  }
  __syncthreads();   // barrier1: fillers arrive clean (no outstanding stores)

  if (wv < 8) {
    // ---- MFMA argmin over 32 code-tiles (LDS-resident, no VMEM) ----
    int n0 = nb0 + (wv << 5);
    float bestA = __uint_as_float(0x7f7fffffu);
    float bestB = __uint_as_float(0x7f7fffffu);
    int rowoff = rl * 72 + g * 8;
    #pragma unroll 8
    for (int t = 0; t < 32; ++t) {
      f32x4 sv = *(const f32x4*)&sw2s[t * 16 + g * 4];
      int tb = t * 1152 + rowoff;
      bf16x8 a0 = *(const bf16x8*)&wlds[tb];
      bf16x8 a1 = *(const bf16x8*)&wlds[tb + 32];
      f32x4 accA = sv, accB = sv;
      accA = __builtin_amdgcn_mfma_f32_16x16x32_bf16(a0, xfA0, accA, 0, 0, 0);
      accA = __builtin_amdgcn_mfma_f32_16x16x32_bf16(a1, xfA1, accA, 0, 0, 0);
      accB = __builtin_amdgcn_mfma_f32_16x16x32_bf16(a0, xfB0, accB, 0, 0, 0);
      accB = __builtin_amdgcn_mfma_f32_16x16x32_bf16(a1, xfB1, accB, 0, 0, 0);
      #pragma unroll
      for (int j = 0; j < 4; ++j) {
        unsigned int ki = (unsigned int)(t * 16 + g * 4 + j);
        bestA = fminf(bestA, __uint_as_float((__float_as_uint(accA[j]) & ~511u) | ki));
        bestB = fminf(bestB, __uint_as_float((__float_as_uint(accB[j]) & ~511u) | ki));
      }
    }
    bestA = fminf(bestA, __shfl_xor(bestA, 16));
    bestA = fminf(bestA, __shfl_xor(bestA, 32));
    bestB = fminf(bestB, __shfl_xor(bestB, 16));
    bestB = fminf(bestB, __shfl_xor(bestB, 32));
    int biA = __float_as_uint(bestA) & 511;
    int biB = __float_as_uint(bestB) & 511;
    float scoreA = __uint_as_float(__float_as_uint(bestA) & ~511u);
    float scoreB = __uint_as_float(__float_as_uint(bestB) & ~511u);

    if (lane < 16) {
      sbi[(wv << 5) + rl] = biA;
      atomicAdd(&hcnt[biA], 1u);
    } else if (lane < 32) {
      sbi[(wv << 5) + 16 + rl] = biB;
      atomicAdd(&hcnt[biB], 1u);
    }
    float dl = (cnA + scoreA) + (cnB + scoreB);   // 4 copies/point in wave
    #pragma unroll
    for (int off = 1; off < 64; off <<= 1) dl += __shfl_xor(dl, off);
    if (lane == 0) lred[wv] = dl * 0.25f;
    (void)n0;
  } else {
    // ---- filler waves: stream 64KB of enc zeros each (contiguous) ----
    int fw = wv - 8;                    // 0..7 -> rows [fw*32, fw*32+32)
    float4* dst = (float4*)(out + ENC_OFF)
                + (((long long)(nb0 + (fw << 5))) << 7);   // row stride 128 f4
    float4 z4 = make_float4(0.f, 0.f, 0.f, 0.f);
    #pragma unroll 8
    for (int i = 0; i < 64; ++i)
      dst[(i << 6) + lane] = z4;        // 4096 float4 = 64KB
  }
  __syncthreads();   // barrier2: fillers' vmcnt(0) drained -> zeros visible

  // ---- the 256 single 1.0s (race-free after barrier2) ----
  if (tid < 256)
    out[ENC_OFF + ((long long)(nb0 + tid) << 9) + sbi[tid]] = 1.0f;

  // ---- quantized: all 16 waves, perfectly coalesced (256B/instr/wave) ----
  {
    int p = tid & 255, half = tid >> 8;          // 4 channel-quarters
    int bip = sbi[p];
    const f32x4* wr4 = (const f32x4*)(W + (bip << 6) + (half << 4));
    float* qp = out + QUANT_OFF + b * 262144 + ((half << 4) * 4096) + hw0b + p;
    #pragma unroll
    for (int cq = 0; cq < 4; ++cq) {
      f32x4 wv4 = wr4[cq];
      qp[(cq * 4 + 0) * 4096] = wv4[0];
      qp[(cq * 4 + 1) * 4096] = wv4[1];
      qp[(cq * 4 + 2) * 4096] = wv4[2];
      qp[(cq * 4 + 3) * 4096] = wv4[3];
    }
  }

  // ---- bookkeeping flush ----
  if (tid < 512) {
    unsigned int hv = hcnt[tid];
    if (hv) atomicAdd(&counts[tid], hv);
  }
  if (tid == 0) {
    float s = 0.0f;
    #pragma unroll
    for (int i = 0; i < 8; ++i) s += lred[i];
    lpart[blockIdx.x] = s;
  }
}

// Tiny finalizer: perplexity from counts, loss from 512 block partials.
__global__ void vq_final(const unsigned int* __restrict__ counts,
                         const float* __restrict__ lpart,
                         float* __restrict__ out) {
  __shared__ float red[8], red2[8];
  int k = threadIdx.x;  // 512 threads
  float pr = (float)counts[k] * (1.0f / 131072.0f);
  float s = pr * logf(pr + 1e-10f);
  float l = lpart[k];
  #pragma unroll
  for (int off = 32; off; off >>= 1) {
    s += __shfl_down(s, off, 64);
    l += __shfl_down(l, off, 64);
  }
  if ((k & 63) == 0) { red[k >> 6] = s; red2[k >> 6] = l; }
  __syncthreads();
  if (k == 0) {
    float H = 0.0f, L = 0.0f;
    #pragma unroll
    for (int i = 0; i < 8; ++i) { H += red[i]; L += red2[i]; }
    out[PERP_OFF] = expf(-H);
    out[0] = 1.25f * L * (1.0f / 8388608.0f);
  }
}

extern "C" void kernel_launch(void* const* d_in, const int* in_sizes, int n_in,
                              void* d_out, int out_size, void* d_ws, size_t ws_size,
                              hipStream_t stream) {
  (void)in_sizes; (void)n_in; (void)out_size; (void)ws_size;
  const float* x = (const float*)d_in[0];
  const float* W = (const float*)d_in[1];
  float* out = (float*)d_out;

  char* ws = (char*)d_ws;
  unsigned int* counts = (unsigned int*)ws;
  float* sw2           = (float*)(ws + 2048);
  float* lpart         = (float*)(ws + 4096);
  unsigned short* w2   = (unsigned short*)(ws + 8192);

  vq_prep<<<512, 64, 0, stream>>>(W, sw2, w2, counts);
  vq_mega<<<512, 1024, 0, stream>>>(x, w2, sw2, W, counts, lpart, out);
  vq_final<<<1, 512, 0, stream>>>(counts, lpart, out);
}